// Round 14
// baseline (57.470 us; speedup 1.0000x reference)
//
#include <hip/hip_runtime.h>
#include <hip/hip_bf16.h>

#define NPIX 9216      // 96*96
#define MKEY 2304      // 48*48

typedef __bf16 bf16x8 __attribute__((ext_vector_type(8)));
typedef float f32x4 __attribute__((ext_vector_type(4)));
typedef float f32x16 __attribute__((ext_vector_type(16)));
typedef short short8v __attribute__((ext_vector_type(8)));
typedef unsigned int u32x4v __attribute__((ext_vector_type(4)));

static __device__ __forceinline__ short f2bs(float f) {
  __bf16 h = (__bf16)f;
  return __builtin_bit_cast(short, h);
}

static __device__ __forceinline__ short4 pack4(const f32x16& acc, int q0, float4 bv, float scl) {
  short4 s;
  s.x = f2bs((acc[q0 + 0] + bv.x) * scl);
  s.y = f2bs((acc[q0 + 1] + bv.y) * scl);
  s.z = f2bs((acc[q0 + 2] + bv.z) * scl);
  s.w = f2bs((acc[q0 + 3] + bv.w) * scl);
  return s;
}

static __device__ __forceinline__ bf16x8 ldf8(const float* p) {
  float4 a = *(const float4*)p;
  float4 b = *(const float4*)(p + 4);
  bf16x8 f;
  f[0] = (__bf16)a.x; f[1] = (__bf16)a.y; f[2] = (__bf16)a.z; f[3] = (__bf16)a.w;
  f[4] = (__bf16)b.x; f[5] = (__bf16)b.y; f[6] = (__bf16)b.z; f[7] = (__bf16)b.w;
  return f;
}

// ---------------- unified MFMA projection kernel, 64-wide tiles (+ meanx partials) ----------------
// jobs 0..287: Q on full x (b = j/144, 64-px tile). Wave w: px group (w>>1)*32, oc = w&1 -> 4 MFMAs.
// jobs 288..359: K+V on pooled x (b = j2/36, 64-m tile). Wave w: set = w>>1 (0=K,1=V), oc = w&1, 2 m-groups.
__global__ __launch_bounds__(256) void proj_kernel(const float* __restrict__ x,
                                                   const float* __restrict__ Wq,
                                                   const float* __restrict__ bq,
                                                   const float* __restrict__ Wk,
                                                   const float* __restrict__ bk,
                                                   const float* __restrict__ Wv,
                                                   const float* __restrict__ bv,
                                                   short* __restrict__ qout,
                                                   short* __restrict__ kout,
                                                   short* __restrict__ vout,
                                                   short* __restrict__ onesb,
                                                   float* __restrict__ mxpart) {
  __shared__ float xs[64 * 64];
  int jid = blockIdx.x;
  int t = threadIdx.x;
  int w = t >> 6, lane = t & 63;
  int c31 = lane & 31, h5 = lane >> 5;
  bool isQ = jid < 288;
  const float QSCALE = 0.25f * 1.44269504088896f;  // fold softmax scale + log2(e)

  // fill bf16 ones buffer for attn (rows 16-31 of PV A-operand)
  if (jid == 0 && t < 160) {
    short8v ov;
#pragma unroll
    for (int j = 0; j < 8; j++) ov[j] = (short)0x3F80;
    *(short8v*)(onesb + t * 8) = ov;
  }

  if (isQ) {
    int b = jid / 144, n0 = (jid % 144) * 64;
#pragma unroll
    for (int i = 0; i < 4; i++) {
      int idx4 = t + 256 * i;  // ci*16 + px4
      int ci = idx4 >> 4, px4 = idx4 & 15;
      float4 v = *(const float4*)(x + ((size_t)(b * 64 + ci)) * NPIX + n0 + px4 * 4);
      *(float4*)(xs + ci * 64 + px4 * 4) = v;
    }
    __syncthreads();

    int px = (w >> 1) * 32 + c31;
    int oc = w & 1;
    bf16x8 xf[4];
#pragma unroll
    for (int ks = 0; ks < 4; ks++) {
      bf16x8 f;
#pragma unroll
      for (int j = 0; j < 8; j++) f[j] = (__bf16)xs[(ks * 16 + h5 * 8 + j) * 64 + px];
      xf[ks] = f;
    }

    // meanx partials: 4 threads per channel over 64 px
    {
      int ci = t >> 2, qq = t & 3;
      const float* row = xs + ci * 64 + qq * 16;
      float s = 0.f;
#pragma unroll
      for (int i = 0; i < 16; i++) s += row[i];
      s += __shfl_xor(s, 1, 64);
      s += __shfl_xor(s, 2, 64);
      if (qq == 0) mxpart[jid * 64 + ci] = s;
    }

    bf16x8 wf[4];
#pragma unroll
    for (int ks = 0; ks < 4; ks++)
      wf[ks] = ldf8(Wq + (size_t)(oc * 32 + c31) * 64 + ks * 16 + h5 * 8);
    f32x16 acc = {};
#pragma unroll
    for (int ks = 0; ks < 4; ks++)
      acc = __builtin_amdgcn_mfma_f32_32x32x16_bf16(wf[ks], xf[ks], acc, 0, 0, 0);

    const float* bb = bq + oc * 32 + 4 * h5;
    float4 bv0 = *(const float4*)(bb);
    float4 bv1 = *(const float4*)(bb + 8);
    float4 bv2 = *(const float4*)(bb + 16);
    float4 bv3 = *(const float4*)(bb + 24);
    short* p0 = qout + (((size_t)(b * 4 + oc * 2)) * NPIX + n0 + px) * 16;
    short* p1 = qout + (((size_t)(b * 4 + oc * 2 + 1)) * NPIX + n0 + px) * 16;
    *(short4*)(p0 + 4 * h5) = pack4(acc, 0, bv0, QSCALE);
    *(short4*)(p0 + 8 + 4 * h5) = pack4(acc, 4, bv1, QSCALE);
    *(short4*)(p1 + 4 * h5) = pack4(acc, 8, bv2, QSCALE);
    *(short4*)(p1 + 8 + 4 * h5) = pack4(acc, 12, bv3, QSCALE);
  } else {
    int j2 = jid - 288;
    int b = j2 / 36, m0 = (j2 % 36) * 64;
#pragma unroll
    for (int it = 0; it < 16; it++) {
      int idx = t + 256 * it;  // ci*64 + pm
      int ci = idx >> 6, pm = idx & 63;
      int m = m0 + pm;
      int i = m / 48, j = m - i * 48;
      const float* s = x + ((size_t)(b * 64 + ci)) * NPIX + (2 * i) * 96 + 2 * j;
      float2 a = *(const float2*)(s);
      float2 c = *(const float2*)(s + 96);
      xs[ci * 64 + pm] = 0.25f * (a.x + a.y + c.x + c.y);
    }
    __syncthreads();

    int set = w >> 1, oc = w & 1;
    const float* W = set ? Wv : Wk;
    const float* bias = set ? bv : bk;

    // preload all B-frags (both m-groups) before sv aliases xs
    bf16x8 xf[2][4];
#pragma unroll
    for (int mg = 0; mg < 2; mg++) {
      int px = mg * 32 + c31;
#pragma unroll
      for (int ks = 0; ks < 4; ks++) {
        bf16x8 f;
#pragma unroll
        for (int j = 0; j < 8; j++) f[j] = (__bf16)xs[(ks * 16 + h5 * 8 + j) * 64 + px];
        xf[mg][ks] = f;
      }
    }
    bf16x8 wf[4];
#pragma unroll
    for (int ks = 0; ks < 4; ks++)
      wf[ks] = ldf8(W + (size_t)(oc * 32 + c31) * 64 + ks * 16 + h5 * 8);
    const float* bb = bias + oc * 32 + 4 * h5;
    float4 bv0 = *(const float4*)(bb);
    float4 bv1 = *(const float4*)(bb + 8);
    float4 bv2 = *(const float4*)(bb + 16);
    float4 bv3 = *(const float4*)(bb + 24);
    __syncthreads();  // all B-frags read; sv may alias xs now

    short* sv = (short*)xs;  // [64 ch][64 m] bf16
#pragma unroll
    for (int mg = 0; mg < 2; mg++) {
      int px = mg * 32 + c31;
      f32x16 acc = {};
#pragma unroll
      for (int ks = 0; ks < 4; ks++)
        acc = __builtin_amdgcn_mfma_f32_32x32x16_bf16(wf[ks], xf[mg][ks], acc, 0, 0, 0);

      if (set == 0) {
        short* p0 = kout + (((size_t)(b * 4 + oc * 2)) * MKEY + m0 + px) * 16;
        short* p1 = kout + (((size_t)(b * 4 + oc * 2 + 1)) * MKEY + m0 + px) * 16;
        *(short4*)(p0 + 4 * h5) = pack4(acc, 0, bv0, 1.0f);
        *(short4*)(p0 + 8 + 4 * h5) = pack4(acc, 4, bv1, 1.0f);
        *(short4*)(p1 + 4 * h5) = pack4(acc, 8, bv2, 1.0f);
        *(short4*)(p1 + 8 + 4 * h5) = pack4(acc, 12, bv3, 1.0f);
      } else {
        float4 bvs[4] = {bv0, bv1, bv2, bv3};
#pragma unroll
        for (int g = 0; g < 4; g++) {
          int rowb = oc * 32 + 8 * g + 4 * h5;
          const float4& bv = bvs[g];
          sv[(rowb + 0) * 64 + px] = f2bs(acc[g * 4 + 0] + bv.x);
          sv[(rowb + 1) * 64 + px] = f2bs(acc[g * 4 + 1] + bv.y);
          sv[(rowb + 2) * 64 + px] = f2bs(acc[g * 4 + 2] + bv.z);
          sv[(rowb + 3) * 64 + px] = f2bs(acc[g * 4 + 3] + bv.w);
        }
      }
    }
    __syncthreads();
    // cooperative coalesced V store: [64 ch][64 m]
#pragma unroll
    for (int kx = 0; kx < 2; kx++) {
      int idx8 = t + 256 * kx;  // co*8 + pm8
      int co = idx8 >> 3, pm8 = idx8 & 7;
      short8v v = *(short8v*)(sv + co * 64 + pm8 * 8);
      *(short8v*)(vout + ((size_t)(b * 64 + co)) * MKEY + m0 + pm8 * 8) = v;
    }
  }
}

// ---------------- MFMA flash attention: in-register P, no online max, 3 q-tiles/wave,
//                  per-32-key half-passes, next-tile prefetch, bf16 out, wave-parallel merge ----------
// grid (96, 4, 2), block 256 = 4 waves. Wave w owns key quarter w (576 keys), q-tiles {q0,q0+32,q0+64}.
// Epilogue: ALL waves publish (l,O) to LDS; waves 0-2 each merge one q-tile (parallel tail).
__global__ __launch_bounds__(256, 3) void attn_kernel(const short* __restrict__ qb,
                                                      const short* __restrict__ kb,
                                                      const short* __restrict__ vb,
                                                      const short* __restrict__ onesb,
                                                      short* __restrict__ aob,
                                                      float* __restrict__ papart) {
  __shared__ __align__(16) float xch[4][3][64 * 12];  // all waves publish (l,_,_,_,O[8]) per lane per q-tile
  int tid = threadIdx.x;
  int w = tid >> 6, lane = tid & 63;
  int c31 = lane & 31, h5 = lane >> 5;
  int h = blockIdx.y, b = blockIdx.z;
  int bh = b * 4 + h;
  int q0 = blockIdx.x * 96;

  // Q B-frags (32x32x16): col=c31 -> query q0+qt*32+c31, k = d = h5*8+j
  bf16x8 qf[3];
#pragma unroll
  for (int qt = 0; qt < 3; qt++)
    qf[qt] = *(const bf16x8*)(qb + ((size_t)bh * NPIX + q0 + qt * 32 + c31) * 16 + h5 * 8);

  const short* kBh = kb + ((size_t)bh * MKEY + w * 576) * 16;
  // PV A-operand source: rows 0-15 = V^T[d][key], rows 16-31 = 1.0 (row-sum trick)
  const short* vsrc = (c31 < 16)
      ? (vb + ((size_t)(b * 64 + h * 16 + c31)) * MKEY + w * 576)
      : onesb;

  f32x16 zf16 = {};
  f32x16 oacc[3] = {zf16, zf16, zf16};  // per q-tile: regs 0-7 = O^T (d rows), reg 8 = l

  // prefetch tile 0
  bf16x8 nka0 = *(const bf16x8*)(kBh + (size_t)(c31) * 16 + h5 * 8);
  bf16x8 nka1 = *(const bf16x8*)(kBh + (size_t)(32 + c31) * 16 + h5 * 8);
  bf16x8 nva0 = *(const bf16x8*)(vsrc + h5 * 8);
  bf16x8 nva1 = *(const bf16x8*)(vsrc + 16 + h5 * 8);
  bf16x8 nva2 = *(const bf16x8*)(vsrc + 32 + h5 * 8);
  bf16x8 nva3 = *(const bf16x8*)(vsrc + 48 + h5 * 8);

  for (int kt = 0; kt < 9; kt++) {
    bf16x8 ka0 = nka0, ka1 = nka1;
    bf16x8 va0 = nva0, va1 = nva1, va2 = nva2, va3 = nva3;
    if (kt < 8) {
      int nb = (kt + 1) * 64;
      nka0 = *(const bf16x8*)(kBh + (size_t)(nb + c31) * 16 + h5 * 8);
      nka1 = *(const bf16x8*)(kBh + (size_t)(nb + 32 + c31) * 16 + h5 * 8);
      nva0 = *(const bf16x8*)(vsrc + nb + h5 * 8);
      nva1 = *(const bf16x8*)(vsrc + nb + 16 + h5 * 8);
      nva2 = *(const bf16x8*)(vsrc + nb + 32 + h5 * 8);
      nva3 = *(const bf16x8*)(vsrc + nb + 48 + h5 * 8);
    }

#pragma unroll
    for (int qt = 0; qt < 3; qt++) {
      // ---- half A: keys kbase..+31 ----
      f32x16 s0 = __builtin_amdgcn_mfma_f32_32x32x16_bf16(ka0, qf[qt], zf16, 0, 0, 0);
      {
        unsigned W[8];
#pragma unroll
        for (int i = 0; i < 8; i++) {
          float p0 = __builtin_amdgcn_exp2f(s0[2 * i]);
          float p1 = __builtin_amdgcn_exp2f(s0[2 * i + 1]);
          unsigned r;
          asm("v_cvt_pk_bf16_f32 %0, %1, %2" : "=v"(r) : "v"(p0), "v"(p1));
          W[i] = r;
        }
        asm("v_permlane32_swap_b32 %0, %1" : "+v"(W[0]), "+v"(W[2]));
        asm("v_permlane32_swap_b32 %0, %1" : "+v"(W[1]), "+v"(W[3]));
        asm("v_permlane32_swap_b32 %0, %1" : "+v"(W[4]), "+v"(W[6]));
        asm("v_permlane32_swap_b32 %0, %1" : "+v"(W[5]), "+v"(W[7]));
        u32x4v w0 = {W[0], W[1], W[2], W[3]};
        u32x4v w1 = {W[4], W[5], W[6], W[7]};
        oacc[qt] = __builtin_amdgcn_mfma_f32_32x32x16_bf16(va0, __builtin_bit_cast(bf16x8, w0), oacc[qt], 0, 0, 0);
        oacc[qt] = __builtin_amdgcn_mfma_f32_32x32x16_bf16(va1, __builtin_bit_cast(bf16x8, w1), oacc[qt], 0, 0, 0);
      }
      // ---- half B: keys kbase+32..+63 ----
      f32x16 s1 = __builtin_amdgcn_mfma_f32_32x32x16_bf16(ka1, qf[qt], zf16, 0, 0, 0);
      {
        unsigned W[8];
#pragma unroll
        for (int i = 0; i < 8; i++) {
          float p0 = __builtin_amdgcn_exp2f(s1[2 * i]);
          float p1 = __builtin_amdgcn_exp2f(s1[2 * i + 1]);
          unsigned r;
          asm("v_cvt_pk_bf16_f32 %0, %1, %2" : "=v"(r) : "v"(p0), "v"(p1));
          W[i] = r;
        }
        asm("v_permlane32_swap_b32 %0, %1" : "+v"(W[0]), "+v"(W[2]));
        asm("v_permlane32_swap_b32 %0, %1" : "+v"(W[1]), "+v"(W[3]));
        asm("v_permlane32_swap_b32 %0, %1" : "+v"(W[4]), "+v"(W[6]));
        asm("v_permlane32_swap_b32 %0, %1" : "+v"(W[5]), "+v"(W[7]));
        u32x4v w2 = {W[0], W[1], W[2], W[3]};
        u32x4v w3 = {W[4], W[5], W[6], W[7]};
        oacc[qt] = __builtin_amdgcn_mfma_f32_32x32x16_bf16(va2, __builtin_bit_cast(bf16x8, w2), oacc[qt], 0, 0, 0);
        oacc[qt] = __builtin_amdgcn_mfma_f32_32x32x16_bf16(va3, __builtin_bit_cast(bf16x8, w3), oacc[qt], 0, 0, 0);
      }
    }
  }

  // all waves publish (l, O) per q-tile
#pragma unroll
  for (int qt = 0; qt < 3; qt++) {
    float* p = xch[w][qt] + lane * 12;
    p[0] = oacc[qt][8];
    f32x4 oa = {oacc[qt][0], oacc[qt][1], oacc[qt][2], oacc[qt][3]};
    f32x4 ob = {oacc[qt][4], oacc[qt][5], oacc[qt][6], oacc[qt][7]};
    *(f32x4*)(p + 4) = oa;
    *(f32x4*)(p + 8) = ob;
  }
  __syncthreads();
  // waves 0-2 each merge one q-tile (parallel epilogue)
  if (w < 3) {
    int qt = w;
    const float* p0 = xch[0][qt] + lane * 12;
    const float* p1 = xch[1][qt] + lane * 12;
    const float* p2 = xch[2][qt] + lane * 12;
    const float* p3 = xch[3][qt] + lane * 12;
    float L = p0[0] + p1[0] + p2[0] + p3[0];
    float rinv = 1.0f / L;
    f32x4 o0a = *(const f32x4*)(p0 + 4), o0b = *(const f32x4*)(p0 + 8);
    f32x4 o1a = *(const f32x4*)(p1 + 4), o1b = *(const f32x4*)(p1 + 8);
    f32x4 o2a = *(const f32x4*)(p2 + 4), o2b = *(const f32x4*)(p2 + 8);
    f32x4 o3a = *(const f32x4*)(p3 + 4), o3b = *(const f32x4*)(p3 + 8);
    // lane (c31,h5): regs 0-3 -> d = h5*4 + 0..3 ; regs 4-7 -> d = h5*4 + 8..11
    float psum[8];
    float r0[4], r1[4];
#pragma unroll
    for (int j = 0; j < 4; j++) {
      r0[j] = (o0a[j] + o1a[j] + o2a[j] + o3a[j]) * rinv;
      r1[j] = (o0b[j] + o1b[j] + o2b[j] + o3b[j]) * rinv;
      psum[j] = r0[j];
      psum[4 + j] = r1[j];
    }
    // bf16 store: [b][h][n][16]
    short* aop = aob + ((size_t)bh * NPIX + q0 + qt * 32 + c31) * 16;
    short4 t0, t1;
    t0.x = f2bs(r0[0]); t0.y = f2bs(r0[1]); t0.z = f2bs(r0[2]); t0.w = f2bs(r0[3]);
    t1.x = f2bs(r1[0]); t1.y = f2bs(r1[1]); t1.z = f2bs(r1[2]); t1.w = f2bs(r1[3]);
    *(short4*)(aop + h5 * 4) = t0;
    *(short4*)(aop + 8 + h5 * 4) = t1;
    // query-sum partials for SE gap: reduce over c31 (h5-preserving), write (block,qt) slot
#pragma unroll
    for (int mask = 1; mask <= 16; mask <<= 1)
#pragma unroll
      for (int k = 0; k < 8; k++) psum[k] += __shfl_xor(psum[k], mask, 64);
    if (c31 == 0) {
      float* pp = papart + ((size_t)(blockIdx.x * 3 + qt) * 8 + bh) * 16;
      f32x4 pa = {psum[0], psum[1], psum[2], psum[3]};
      f32x4 pb = {psum[4], psum[5], psum[6], psum[7]};
      *(f32x4*)(pp + h5 * 4) = pa;
      *(f32x4*)(pp + 8 + h5 * 4) = pb;
    }
  }
}

// ------------- SE + gate: gfac[b][c] = gate * ca  (sums mxpart/papart partials, 256 thr) -------------
__global__ __launch_bounds__(256) void se_gate_kernel(const float* __restrict__ mxpart,
                                                      const float* __restrict__ papart,
                                                      const float* __restrict__ Wo,
                                                      const float* __restrict__ bo,
                                                      const float* __restrict__ W1,
                                                      const float* __restrict__ b1,
                                                      const float* __restrict__ W2,
                                                      const float* __restrict__ b2,
                                                      const float* __restrict__ Wg,
                                                      const float* __restrict__ bg,
                                                      float* __restrict__ gfac) {
  __shared__ float ma_s[128], gap_s[128], ca_s[128], mx_s[128];
  __shared__ float ma2[128], mx2[128];
  int t = threadIdx.x;
  int tc = t & 127;        // channel slot (b*64+c)
  int half = t >> 7;       // 0 or 1: split the partial sums
  int b = tc >> 6, c = tc & 63;
  int hh = c >> 4, d = c & 15;
  // papart: 288 slots split 144/144; mxpart: 144 per batch split 72/72
  float sa = 0.f;
  for (int bx = half * 144; bx < half * 144 + 144; bx++)
    sa += papart[((size_t)bx * 8 + b * 4 + hh) * 16 + d];
  float sx = 0.f;
  for (int j = half * 72; j < half * 72 + 72; j++)
    sx += mxpart[(b * 144 + j) * 64 + c];
  if (half == 0) { ma_s[tc] = sa; mx_s[tc] = sx; }
  else { ma2[tc] = sa; mx2[tc] = sx; }
  __syncthreads();
  if (t < 128) {
    ma_s[t] = (ma_s[t] + ma2[t]) * (1.f / NPIX);
    mx_s[t] = (mx_s[t] + mx2[t]) * (1.f / NPIX);
  }
  __syncthreads();
  if (t < 128) {
    float gp = bo[c];
    for (int ci = 0; ci < 64; ci++) gp += Wo[c * 64 + ci] * ma_s[b * 64 + ci];
    gap_s[t] = gp;
  }
  __syncthreads();
  if (t < 128) {
    float se[4];
#pragma unroll
    for (int i = 0; i < 4; i++) {
      float s = b1[i];
      for (int cc = 0; cc < 64; cc++) s += W1[i * 64 + cc] * gap_s[b * 64 + cc];
      se[i] = fmaxf(s, 0.f);
    }
    float cav = b2[c];
#pragma unroll
    for (int i = 0; i < 4; i++) cav += W2[c * 4 + i] * se[i];
    cav = 1.f / (1.f + __expf(-cav));
    ca_s[t] = cav;
  }
  __syncthreads();
  if (t < 128) {
    float gv = bg[c];
    for (int j = 0; j < 64; j++) gv += Wg[c * 128 + j] * mx_s[b * 64 + j];
    for (int j = 0; j < 64; j++)
      gv += Wg[c * 128 + 64 + j] * (mx_s[b * 64 + j] + ca_s[b * 64 + j] * gap_s[b * 64 + j]);
    gv = 1.f / (1.f + __expf(-gv));
    gfac[t] = gv * ca_s[t];
  }
}

// ------------- MFMA o-projection + gated residual blend -> d_out (no LDS, 1 wave/block) -------------
// B-frag ks = aob[b][ks][px][h5*8+j] bf16 (head ks == cin slice ks), A = Wo.
__global__ __launch_bounds__(64) void oproj_final_kernel(const short* __restrict__ aob,
                                                         const float* __restrict__ W,
                                                         const float* __restrict__ bias,
                                                         const float* __restrict__ x,
                                                         const float* __restrict__ gfac,
                                                         float* __restrict__ out) {
  int b = blockIdx.y;
  int n0 = blockIdx.x * 32;
  int lane = threadIdx.x;
  int c31 = lane & 31, h5 = lane >> 5;
  int px = n0 + c31;

  // B-frags: direct bf16 16B loads
  bf16x8 xf[4];
#pragma unroll
  for (int ks = 0; ks < 4; ks++)
    xf[ks] = *(const bf16x8*)(aob + (((size_t)(b * 4 + ks)) * NPIX + px) * 16 + h5 * 8);

#pragma unroll
  for (int oc = 0; oc < 2; oc++) {
    bf16x8 wf[4];
#pragma unroll
    for (int ks = 0; ks < 4; ks++)
      wf[ks] = ldf8(W + (size_t)(oc * 32 + c31) * 64 + ks * 16 + h5 * 8);
    f32x16 acc = {};
#pragma unroll
    for (int ks = 0; ks < 4; ks++)
      acc = __builtin_amdgcn_mfma_f32_32x32x16_bf16(wf[ks], xf[ks], acc, 0, 0, 0);

    const float* bb = bias + oc * 32 + 4 * h5;
    const float* gg = gfac + b * 64 + oc * 32 + 4 * h5;
#pragma unroll
    for (int grp = 0; grp < 4; grp++) {
      float4 bv = *(const float4*)(bb + 8 * grp);
      float4 gf = *(const float4*)(gg + 8 * grp);
      int co = oc * 32 + 8 * grp + 4 * h5;
      const float* xp = x + ((size_t)(b * 64 + co)) * NPIX + px;
      float* op = out + ((size_t)(b * 64 + co)) * NPIX + px;
      op[0 * NPIX] = xp[0 * NPIX] + gf.x * (acc[grp * 4 + 0] + bv.x);
      op[1 * NPIX] = xp[1 * NPIX] + gf.y * (acc[grp * 4 + 1] + bv.y);
      op[2 * NPIX] = xp[2 * NPIX] + gf.z * (acc[grp * 4 + 2] + bv.z);
      op[3 * NPIX] = xp[3 * NPIX] + gf.w * (acc[grp * 4 + 3] + bv.w);
    }
  }
}

extern "C" void kernel_launch(void* const* d_in, const int* in_sizes, int n_in,
                              void* d_out, int out_size, void* d_ws, size_t ws_size,
                              hipStream_t stream) {
  const float* x  = (const float*)d_in[0];
  const float* Wq = (const float*)d_in[1];
  const float* bq = (const float*)d_in[2];
  const float* Wk = (const float*)d_in[3];
  const float* bk = (const float*)d_in[4];
  const float* Wv = (const float*)d_in[5];
  const float* bv = (const float*)d_in[6];
  const float* Wo = (const float*)d_in[7];
  const float* bo = (const float*)d_in[8];
  const float* W1 = (const float*)d_in[9];
  const float* b1 = (const float*)d_in[10];
  const float* W2 = (const float*)d_in[11];
  const float* b2 = (const float*)d_in[12];
  const float* Wg = (const float*)d_in[13];
  const float* bg = (const float*)d_in[14];

  char* w = (char*)d_ws;
  short* qb16   = (short*)w; w += 2359296;   // [2][4][9216][16] bf16
  short* kb16   = (short*)w; w += 589824;    // [2][4][2304][16] bf16
  short* vb16   = (short*)w; w += 589824;    // [2][64][2304] bf16 (V^T per head)
  short* aob    = (short*)w; w += 2359296;   // [2][4][9216][16] bf16 attention output
  float* mxpart = (float*)w; w += 73728;     // [288][64] per-block x channel sums
  float* papart = (float*)w; w += 147456;    // [288][8][16] per-(block,qt) attn-out query sums
  float* gfac   = (float*)w; w += 512;
  short* onesb  = (short*)w; w += 2560;      // 1280 bf16 ones

  proj_kernel<<<360, 256, 0, stream>>>(x, Wq, bq, Wk, bk, Wv, bv, qb16, kb16, vb16, onesb, mxpart);
  attn_kernel<<<dim3(96, 4, 2), 256, 0, stream>>>(qb16, kb16, vb16, onesb, aob, papart);
  se_gate_kernel<<<1, 256, 0, stream>>>(mxpart, papart, Wo, bo, W1, b1, W2, b2, Wg, bg, gfac);
  oproj_final_kernel<<<dim3(288, 2), 64, 0, stream>>>(aob, Wo, bo, x, gfac, (float*)d_out);
}

// Round 15
// 53.833 us; speedup vs baseline: 1.0676x; 1.0676x over previous
//
#include <hip/hip_runtime.h>
#include <hip/hip_bf16.h>

#define NPIX 9216      // 96*96
#define MKEY 2304      // 48*48

typedef __bf16 bf16x8 __attribute__((ext_vector_type(8)));
typedef float f32x4 __attribute__((ext_vector_type(4)));
typedef float f32x16 __attribute__((ext_vector_type(16)));
typedef short short8v __attribute__((ext_vector_type(8)));
typedef unsigned int u32x4v __attribute__((ext_vector_type(4)));

static __device__ __forceinline__ short f2bs(float f) {
  __bf16 h = (__bf16)f;
  return __builtin_bit_cast(short, h);
}

static __device__ __forceinline__ short4 pack4(const f32x16& acc, int q0, float4 bv, float scl) {
  short4 s;
  s.x = f2bs((acc[q0 + 0] + bv.x) * scl);
  s.y = f2bs((acc[q0 + 1] + bv.y) * scl);
  s.z = f2bs((acc[q0 + 2] + bv.z) * scl);
  s.w = f2bs((acc[q0 + 3] + bv.w) * scl);
  return s;
}

static __device__ __forceinline__ bf16x8 ldf8(const float* p) {
  float4 a = *(const float4*)p;
  float4 b = *(const float4*)(p + 4);
  bf16x8 f;
  f[0] = (__bf16)a.x; f[1] = (__bf16)a.y; f[2] = (__bf16)a.z; f[3] = (__bf16)a.w;
  f[4] = (__bf16)b.x; f[5] = (__bf16)b.y; f[6] = (__bf16)b.z; f[7] = (__bf16)b.w;
  return f;
}

// ---------------- unified MFMA projection kernel, 64-wide tiles (+ meanx partials) ----------------
// jobs 0..287: Q on full x (b = j/144, 64-px tile). Wave w: px group (w>>1)*32, oc = w&1 -> 4 MFMAs.
// jobs 288..359: K+V on pooled x (b = j2/36, 64-m tile). Wave w: set = w>>1 (0=K,1=V), oc = w&1, 2 m-groups.
__global__ __launch_bounds__(256) void proj_kernel(const float* __restrict__ x,
                                                   const float* __restrict__ Wq,
                                                   const float* __restrict__ bq,
                                                   const float* __restrict__ Wk,
                                                   const float* __restrict__ bk,
                                                   const float* __restrict__ Wv,
                                                   const float* __restrict__ bv,
                                                   short* __restrict__ qout,
                                                   short* __restrict__ kout,
                                                   short* __restrict__ vout,
                                                   short* __restrict__ onesb,
                                                   float* __restrict__ mxpart) {
  __shared__ float xs[64 * 64];
  int jid = blockIdx.x;
  int t = threadIdx.x;
  int w = t >> 6, lane = t & 63;
  int c31 = lane & 31, h5 = lane >> 5;
  bool isQ = jid < 288;
  const float QSCALE = 0.25f * 1.44269504088896f;  // fold softmax scale + log2(e)

  // fill bf16 ones buffer for attn (rows 16-31 of PV A-operand)
  if (jid == 0 && t < 160) {
    short8v ov;
#pragma unroll
    for (int j = 0; j < 8; j++) ov[j] = (short)0x3F80;
    *(short8v*)(onesb + t * 8) = ov;
  }

  if (isQ) {
    int b = jid / 144, n0 = (jid % 144) * 64;
#pragma unroll
    for (int i = 0; i < 4; i++) {
      int idx4 = t + 256 * i;  // ci*16 + px4
      int ci = idx4 >> 4, px4 = idx4 & 15;
      float4 v = *(const float4*)(x + ((size_t)(b * 64 + ci)) * NPIX + n0 + px4 * 4);
      *(float4*)(xs + ci * 64 + px4 * 4) = v;
    }
    __syncthreads();

    int px = (w >> 1) * 32 + c31;
    int oc = w & 1;
    bf16x8 xf[4];
#pragma unroll
    for (int ks = 0; ks < 4; ks++) {
      bf16x8 f;
#pragma unroll
      for (int j = 0; j < 8; j++) f[j] = (__bf16)xs[(ks * 16 + h5 * 8 + j) * 64 + px];
      xf[ks] = f;
    }

    // meanx partials: 4 threads per channel over 64 px
    {
      int ci = t >> 2, qq = t & 3;
      const float* row = xs + ci * 64 + qq * 16;
      float s = 0.f;
#pragma unroll
      for (int i = 0; i < 16; i++) s += row[i];
      s += __shfl_xor(s, 1, 64);
      s += __shfl_xor(s, 2, 64);
      if (qq == 0) mxpart[jid * 64 + ci] = s;
    }

    bf16x8 wf[4];
#pragma unroll
    for (int ks = 0; ks < 4; ks++)
      wf[ks] = ldf8(Wq + (size_t)(oc * 32 + c31) * 64 + ks * 16 + h5 * 8);
    f32x16 acc = {};
#pragma unroll
    for (int ks = 0; ks < 4; ks++)
      acc = __builtin_amdgcn_mfma_f32_32x32x16_bf16(wf[ks], xf[ks], acc, 0, 0, 0);

    const float* bb = bq + oc * 32 + 4 * h5;
    float4 bv0 = *(const float4*)(bb);
    float4 bv1 = *(const float4*)(bb + 8);
    float4 bv2 = *(const float4*)(bb + 16);
    float4 bv3 = *(const float4*)(bb + 24);
    short* p0 = qout + (((size_t)(b * 4 + oc * 2)) * NPIX + n0 + px) * 16;
    short* p1 = qout + (((size_t)(b * 4 + oc * 2 + 1)) * NPIX + n0 + px) * 16;
    *(short4*)(p0 + 4 * h5) = pack4(acc, 0, bv0, QSCALE);
    *(short4*)(p0 + 8 + 4 * h5) = pack4(acc, 4, bv1, QSCALE);
    *(short4*)(p1 + 4 * h5) = pack4(acc, 8, bv2, QSCALE);
    *(short4*)(p1 + 8 + 4 * h5) = pack4(acc, 12, bv3, QSCALE);
  } else {
    int j2 = jid - 288;
    int b = j2 / 36, m0 = (j2 % 36) * 64;
#pragma unroll
    for (int it = 0; it < 16; it++) {
      int idx = t + 256 * it;  // ci*64 + pm
      int ci = idx >> 6, pm = idx & 63;
      int m = m0 + pm;
      int i = m / 48, j = m - i * 48;
      const float* s = x + ((size_t)(b * 64 + ci)) * NPIX + (2 * i) * 96 + 2 * j;
      float2 a = *(const float2*)(s);
      float2 c = *(const float2*)(s + 96);
      xs[ci * 64 + pm] = 0.25f * (a.x + a.y + c.x + c.y);
    }
    __syncthreads();

    int set = w >> 1, oc = w & 1;
    const float* W = set ? Wv : Wk;
    const float* bias = set ? bv : bk;

    // preload all B-frags (both m-groups) before sv aliases xs
    bf16x8 xf[2][4];
#pragma unroll
    for (int mg = 0; mg < 2; mg++) {
      int px = mg * 32 + c31;
#pragma unroll
      for (int ks = 0; ks < 4; ks++) {
        bf16x8 f;
#pragma unroll
        for (int j = 0; j < 8; j++) f[j] = (__bf16)xs[(ks * 16 + h5 * 8 + j) * 64 + px];
        xf[mg][ks] = f;
      }
    }
    bf16x8 wf[4];
#pragma unroll
    for (int ks = 0; ks < 4; ks++)
      wf[ks] = ldf8(W + (size_t)(oc * 32 + c31) * 64 + ks * 16 + h5 * 8);
    const float* bb = bias + oc * 32 + 4 * h5;
    float4 bv0 = *(const float4*)(bb);
    float4 bv1 = *(const float4*)(bb + 8);
    float4 bv2 = *(const float4*)(bb + 16);
    float4 bv3 = *(const float4*)(bb + 24);
    __syncthreads();  // all B-frags read; sv may alias xs now

    short* sv = (short*)xs;  // [64 ch][64 m] bf16
#pragma unroll
    for (int mg = 0; mg < 2; mg++) {
      int px = mg * 32 + c31;
      f32x16 acc = {};
#pragma unroll
      for (int ks = 0; ks < 4; ks++)
        acc = __builtin_amdgcn_mfma_f32_32x32x16_bf16(wf[ks], xf[mg][ks], acc, 0, 0, 0);

      if (set == 0) {
        short* p0 = kout + (((size_t)(b * 4 + oc * 2)) * MKEY + m0 + px) * 16;
        short* p1 = kout + (((size_t)(b * 4 + oc * 2 + 1)) * MKEY + m0 + px) * 16;
        *(short4*)(p0 + 4 * h5) = pack4(acc, 0, bv0, 1.0f);
        *(short4*)(p0 + 8 + 4 * h5) = pack4(acc, 4, bv1, 1.0f);
        *(short4*)(p1 + 4 * h5) = pack4(acc, 8, bv2, 1.0f);
        *(short4*)(p1 + 8 + 4 * h5) = pack4(acc, 12, bv3, 1.0f);
      } else {
        float4 bvs[4] = {bv0, bv1, bv2, bv3};
#pragma unroll
        for (int g = 0; g < 4; g++) {
          int rowb = oc * 32 + 8 * g + 4 * h5;
          const float4& bv = bvs[g];
          sv[(rowb + 0) * 64 + px] = f2bs(acc[g * 4 + 0] + bv.x);
          sv[(rowb + 1) * 64 + px] = f2bs(acc[g * 4 + 1] + bv.y);
          sv[(rowb + 2) * 64 + px] = f2bs(acc[g * 4 + 2] + bv.z);
          sv[(rowb + 3) * 64 + px] = f2bs(acc[g * 4 + 3] + bv.w);
        }
      }
    }
    __syncthreads();
    // cooperative coalesced V store: [64 ch][64 m]
#pragma unroll
    for (int kx = 0; kx < 2; kx++) {
      int idx8 = t + 256 * kx;  // co*8 + pm8
      int co = idx8 >> 3, pm8 = idx8 & 7;
      short8v v = *(short8v*)(sv + co * 64 + pm8 * 8);
      *(short8v*)(vout + ((size_t)(b * 64 + co)) * MKEY + m0 + pm8 * 8) = v;
    }
  }
}

// ---------------- MFMA flash attention: in-register P, no online max, 3 q-tiles/wave,
//                  per-32-key half-passes, next-tile register prefetch, bf16 out + fused partials ----
// grid (96, 4, 2), block 256 = 4 waves. Wave w owns key quarter w (576 keys), q-tiles {q0,q0+32,q0+64}.
__global__ __launch_bounds__(256, 3) void attn_kernel(const short* __restrict__ qb,
                                                      const short* __restrict__ kb,
                                                      const short* __restrict__ vb,
                                                      const short* __restrict__ onesb,
                                                      short* __restrict__ aob,
                                                      float* __restrict__ papart) {
  __shared__ __align__(16) float xch[3][3][64 * 12];  // waves 1-3 publish (l,_,_,_,O[8]) per lane per q-tile
  int tid = threadIdx.x;
  int w = tid >> 6, lane = tid & 63;
  int c31 = lane & 31, h5 = lane >> 5;
  int h = blockIdx.y, b = blockIdx.z;
  int bh = b * 4 + h;
  int q0 = blockIdx.x * 96;

  // Q B-frags (32x32x16): col=c31 -> query q0+qt*32+c31, k = d = h5*8+j
  bf16x8 qf[3];
#pragma unroll
  for (int qt = 0; qt < 3; qt++)
    qf[qt] = *(const bf16x8*)(qb + ((size_t)bh * NPIX + q0 + qt * 32 + c31) * 16 + h5 * 8);

  const short* kBh = kb + ((size_t)bh * MKEY + w * 576) * 16;
  // PV A-operand source: rows 0-15 = V^T[d][key], rows 16-31 = 1.0 (row-sum trick)
  const short* vsrc = (c31 < 16)
      ? (vb + ((size_t)(b * 64 + h * 16 + c31)) * MKEY + w * 576)
      : onesb;

  f32x16 zf16 = {};
  f32x16 oacc[3] = {zf16, zf16, zf16};  // per q-tile: regs 0-7 = O^T (d rows), reg 8 = l

  // prefetch tile 0
  bf16x8 nka0 = *(const bf16x8*)(kBh + (size_t)(c31) * 16 + h5 * 8);
  bf16x8 nka1 = *(const bf16x8*)(kBh + (size_t)(32 + c31) * 16 + h5 * 8);
  bf16x8 nva0 = *(const bf16x8*)(vsrc + h5 * 8);
  bf16x8 nva1 = *(const bf16x8*)(vsrc + 16 + h5 * 8);
  bf16x8 nva2 = *(const bf16x8*)(vsrc + 32 + h5 * 8);
  bf16x8 nva3 = *(const bf16x8*)(vsrc + 48 + h5 * 8);

  for (int kt = 0; kt < 9; kt++) {
    bf16x8 ka0 = nka0, ka1 = nka1;
    bf16x8 va0 = nva0, va1 = nva1, va2 = nva2, va3 = nva3;
    if (kt < 8) {
      int nb = (kt + 1) * 64;
      nka0 = *(const bf16x8*)(kBh + (size_t)(nb + c31) * 16 + h5 * 8);
      nka1 = *(const bf16x8*)(kBh + (size_t)(nb + 32 + c31) * 16 + h5 * 8);
      nva0 = *(const bf16x8*)(vsrc + nb + h5 * 8);
      nva1 = *(const bf16x8*)(vsrc + nb + 16 + h5 * 8);
      nva2 = *(const bf16x8*)(vsrc + nb + 32 + h5 * 8);
      nva3 = *(const bf16x8*)(vsrc + nb + 48 + h5 * 8);
    }

#pragma unroll
    for (int qt = 0; qt < 3; qt++) {
      // ---- half A: keys kbase..+31 ----
      f32x16 s0 = __builtin_amdgcn_mfma_f32_32x32x16_bf16(ka0, qf[qt], zf16, 0, 0, 0);
      {
        unsigned W[8];
#pragma unroll
        for (int i = 0; i < 8; i++) {
          float p0 = __builtin_amdgcn_exp2f(s0[2 * i]);
          float p1 = __builtin_amdgcn_exp2f(s0[2 * i + 1]);
          unsigned r;
          asm("v_cvt_pk_bf16_f32 %0, %1, %2" : "=v"(r) : "v"(p0), "v"(p1));
          W[i] = r;
        }
        asm("v_permlane32_swap_b32 %0, %1" : "+v"(W[0]), "+v"(W[2]));
        asm("v_permlane32_swap_b32 %0, %1" : "+v"(W[1]), "+v"(W[3]));
        asm("v_permlane32_swap_b32 %0, %1" : "+v"(W[4]), "+v"(W[6]));
        asm("v_permlane32_swap_b32 %0, %1" : "+v"(W[5]), "+v"(W[7]));
        u32x4v w0 = {W[0], W[1], W[2], W[3]};
        u32x4v w1 = {W[4], W[5], W[6], W[7]};
        oacc[qt] = __builtin_amdgcn_mfma_f32_32x32x16_bf16(va0, __builtin_bit_cast(bf16x8, w0), oacc[qt], 0, 0, 0);
        oacc[qt] = __builtin_amdgcn_mfma_f32_32x32x16_bf16(va1, __builtin_bit_cast(bf16x8, w1), oacc[qt], 0, 0, 0);
      }
      // ---- half B: keys kbase+32..+63 ----
      f32x16 s1 = __builtin_amdgcn_mfma_f32_32x32x16_bf16(ka1, qf[qt], zf16, 0, 0, 0);
      {
        unsigned W[8];
#pragma unroll
        for (int i = 0; i < 8; i++) {
          float p0 = __builtin_amdgcn_exp2f(s1[2 * i]);
          float p1 = __builtin_amdgcn_exp2f(s1[2 * i + 1]);
          unsigned r;
          asm("v_cvt_pk_bf16_f32 %0, %1, %2" : "=v"(r) : "v"(p0), "v"(p1));
          W[i] = r;
        }
        asm("v_permlane32_swap_b32 %0, %1" : "+v"(W[0]), "+v"(W[2]));
        asm("v_permlane32_swap_b32 %0, %1" : "+v"(W[1]), "+v"(W[3]));
        asm("v_permlane32_swap_b32 %0, %1" : "+v"(W[4]), "+v"(W[6]));
        asm("v_permlane32_swap_b32 %0, %1" : "+v"(W[5]), "+v"(W[7]));
        u32x4v w2 = {W[0], W[1], W[2], W[3]};
        u32x4v w3 = {W[4], W[5], W[6], W[7]};
        oacc[qt] = __builtin_amdgcn_mfma_f32_32x32x16_bf16(va2, __builtin_bit_cast(bf16x8, w2), oacc[qt], 0, 0, 0);
        oacc[qt] = __builtin_amdgcn_mfma_f32_32x32x16_bf16(va3, __builtin_bit_cast(bf16x8, w3), oacc[qt], 0, 0, 0);
      }
    }
  }

  // 4-way key-split merge via LDS: plain sums of l and O per q-tile (no m exchange needed)
  if (w > 0) {
#pragma unroll
    for (int qt = 0; qt < 3; qt++) {
      float* p = xch[w - 1][qt] + lane * 12;
      p[0] = oacc[qt][8];
      f32x4 oa = {oacc[qt][0], oacc[qt][1], oacc[qt][2], oacc[qt][3]};
      f32x4 ob = {oacc[qt][4], oacc[qt][5], oacc[qt][6], oacc[qt][7]};
      *(f32x4*)(p + 4) = oa;
      *(f32x4*)(p + 8) = ob;
    }
  }
  __syncthreads();
  if (w == 0) {
    float psum[8];
#pragma unroll
    for (int k = 0; k < 8; k++) psum[k] = 0.f;
#pragma unroll
    for (int qt = 0; qt < 3; qt++) {
      const float* p1 = xch[0][qt] + lane * 12;
      const float* p2 = xch[1][qt] + lane * 12;
      const float* p3 = xch[2][qt] + lane * 12;
      float L = oacc[qt][8] + p1[0] + p2[0] + p3[0];
      float rinv = 1.0f / L;
      f32x4 o1a = *(const f32x4*)(p1 + 4), o1b = *(const f32x4*)(p1 + 8);
      f32x4 o2a = *(const f32x4*)(p2 + 4), o2b = *(const f32x4*)(p2 + 8);
      f32x4 o3a = *(const f32x4*)(p3 + 4), o3b = *(const f32x4*)(p3 + 8);
      // lane (c31,h5): regs 0-3 -> d = h5*4 + 0..3 ; regs 4-7 -> d = h5*4 + 8..11
      float r0[4], r1[4];
#pragma unroll
      for (int j = 0; j < 4; j++) {
        r0[j] = (oacc[qt][j] + o1a[j] + o2a[j] + o3a[j]) * rinv;
        r1[j] = (oacc[qt][4 + j] + o1b[j] + o2b[j] + o3b[j]) * rinv;
        psum[j] += r0[j];
        psum[4 + j] += r1[j];
      }
      // bf16 store: [b][h][n][16]
      short* aop = aob + ((size_t)bh * NPIX + q0 + qt * 32 + c31) * 16;
      short4 t0, t1;
      t0.x = f2bs(r0[0]); t0.y = f2bs(r0[1]); t0.z = f2bs(r0[2]); t0.w = f2bs(r0[3]);
      t1.x = f2bs(r1[0]); t1.y = f2bs(r1[1]); t1.z = f2bs(r1[2]); t1.w = f2bs(r1[3]);
      *(short4*)(aop + h5 * 4) = t0;
      *(short4*)(aop + 8 + h5 * 4) = t1;
    }
    // query-sum partials for SE gap: reduce over c31 (h5-preserving), write block slot
#pragma unroll
    for (int mask = 1; mask <= 16; mask <<= 1)
#pragma unroll
      for (int k = 0; k < 8; k++) psum[k] += __shfl_xor(psum[k], mask, 64);
    if (c31 == 0) {
      float* pp = papart + ((size_t)blockIdx.x * 8 + bh) * 16;
      f32x4 pa = {psum[0], psum[1], psum[2], psum[3]};
      f32x4 pb = {psum[4], psum[5], psum[6], psum[7]};
      *(f32x4*)(pp + h5 * 4) = pa;
      *(f32x4*)(pp + 8 + h5 * 4) = pb;
    }
  }
}

// ------------- SE + gate: gfac[b][c] = gate * ca  (sums mxpart/papart partials, 256 thr) -------------
__global__ __launch_bounds__(256) void se_gate_kernel(const float* __restrict__ mxpart,
                                                      const float* __restrict__ papart,
                                                      const float* __restrict__ Wo,
                                                      const float* __restrict__ bo,
                                                      const float* __restrict__ W1,
                                                      const float* __restrict__ b1,
                                                      const float* __restrict__ W2,
                                                      const float* __restrict__ b2,
                                                      const float* __restrict__ Wg,
                                                      const float* __restrict__ bg,
                                                      float* __restrict__ gfac) {
  __shared__ float ma_s[128], gap_s[128], ca_s[128], mx_s[128];
  __shared__ float ma2[128], mx2[128];
  int t = threadIdx.x;
  int tc = t & 127;        // channel slot (b*64+c)
  int half = t >> 7;       // 0 or 1: split the partial sums
  int b = tc >> 6, c = tc & 63;
  int hh = c >> 4, d = c & 15;
  // papart: 96 blocks split 48/48; mxpart: 144 per batch split 72/72
  float sa = 0.f;
  for (int bx = half * 48; bx < half * 48 + 48; bx++)
    sa += papart[((size_t)bx * 8 + b * 4 + hh) * 16 + d];
  float sx = 0.f;
  for (int j = half * 72; j < half * 72 + 72; j++)
    sx += mxpart[(b * 144 + j) * 64 + c];
  if (half == 0) { ma_s[tc] = sa; mx_s[tc] = sx; }
  else { ma2[tc] = sa; mx2[tc] = sx; }
  __syncthreads();
  if (t < 128) {
    ma_s[t] = (ma_s[t] + ma2[t]) * (1.f / NPIX);
    mx_s[t] = (mx_s[t] + mx2[t]) * (1.f / NPIX);
  }
  __syncthreads();
  if (t < 128) {
    float gp = bo[c];
    for (int ci = 0; ci < 64; ci++) gp += Wo[c * 64 + ci] * ma_s[b * 64 + ci];
    gap_s[t] = gp;
  }
  __syncthreads();
  if (t < 128) {
    float se[4];
#pragma unroll
    for (int i = 0; i < 4; i++) {
      float s = b1[i];
      for (int cc = 0; cc < 64; cc++) s += W1[i * 64 + cc] * gap_s[b * 64 + cc];
      se[i] = fmaxf(s, 0.f);
    }
    float cav = b2[c];
#pragma unroll
    for (int i = 0; i < 4; i++) cav += W2[c * 4 + i] * se[i];
    cav = 1.f / (1.f + __expf(-cav));
    ca_s[t] = cav;
  }
  __syncthreads();
  if (t < 128) {
    float gv = bg[c];
    for (int j = 0; j < 64; j++) gv += Wg[c * 128 + j] * mx_s[b * 64 + j];
    for (int j = 0; j < 64; j++)
      gv += Wg[c * 128 + 64 + j] * (mx_s[b * 64 + j] + ca_s[b * 64 + j] * gap_s[b * 64 + j]);
    gv = 1.f / (1.f + __expf(-gv));
    gfac[t] = gv * ca_s[t];
  }
}

// ------------- MFMA o-projection + gated residual blend -> d_out (no LDS, 1 wave/block) -------------
// B-frag ks = aob[b][ks][px][h5*8+j] bf16 (head ks == cin slice ks), A = Wo.
__global__ __launch_bounds__(64) void oproj_final_kernel(const short* __restrict__ aob,
                                                         const float* __restrict__ W,
                                                         const float* __restrict__ bias,
                                                         const float* __restrict__ x,
                                                         const float* __restrict__ gfac,
                                                         float* __restrict__ out) {
  int b = blockIdx.y;
  int n0 = blockIdx.x * 32;
  int lane = threadIdx.x;
  int c31 = lane & 31, h5 = lane >> 5;
  int px = n0 + c31;

  // B-frags: direct bf16 16B loads
  bf16x8 xf[4];
#pragma unroll
  for (int ks = 0; ks < 4; ks++)
    xf[ks] = *(const bf16x8*)(aob + (((size_t)(b * 4 + ks)) * NPIX + px) * 16 + h5 * 8);

#pragma unroll
  for (int oc = 0; oc < 2; oc++) {
    bf16x8 wf[4];
#pragma unroll
    for (int ks = 0; ks < 4; ks++)
      wf[ks] = ldf8(W + (size_t)(oc * 32 + c31) * 64 + ks * 16 + h5 * 8);
    f32x16 acc = {};
#pragma unroll
    for (int ks = 0; ks < 4; ks++)
      acc = __builtin_amdgcn_mfma_f32_32x32x16_bf16(wf[ks], xf[ks], acc, 0, 0, 0);

    const float* bb = bias + oc * 32 + 4 * h5;
    const float* gg = gfac + b * 64 + oc * 32 + 4 * h5;
#pragma unroll
    for (int grp = 0; grp < 4; grp++) {
      float4 bv = *(const float4*)(bb + 8 * grp);
      float4 gf = *(const float4*)(gg + 8 * grp);
      int co = oc * 32 + 8 * grp + 4 * h5;
      const float* xp = x + ((size_t)(b * 64 + co)) * NPIX + px;
      float* op = out + ((size_t)(b * 64 + co)) * NPIX + px;
      op[0 * NPIX] = xp[0 * NPIX] + gf.x * (acc[grp * 4 + 0] + bv.x);
      op[1 * NPIX] = xp[1 * NPIX] + gf.y * (acc[grp * 4 + 1] + bv.y);
      op[2 * NPIX] = xp[2 * NPIX] + gf.z * (acc[grp * 4 + 2] + bv.z);
      op[3 * NPIX] = xp[3 * NPIX] + gf.w * (acc[grp * 4 + 3] + bv.w);
    }
  }
}

extern "C" void kernel_launch(void* const* d_in, const int* in_sizes, int n_in,
                              void* d_out, int out_size, void* d_ws, size_t ws_size,
                              hipStream_t stream) {
  const float* x  = (const float*)d_in[0];
  const float* Wq = (const float*)d_in[1];
  const float* bq = (const float*)d_in[2];
  const float* Wk = (const float*)d_in[3];
  const float* bk = (const float*)d_in[4];
  const float* Wv = (const float*)d_in[5];
  const float* bv = (const float*)d_in[6];
  const float* Wo = (const float*)d_in[7];
  const float* bo = (const float*)d_in[8];
  const float* W1 = (const float*)d_in[9];
  const float* b1 = (const float*)d_in[10];
  const float* W2 = (const float*)d_in[11];
  const float* b2 = (const float*)d_in[12];
  const float* Wg = (const float*)d_in[13];
  const float* bg = (const float*)d_in[14];

  char* w = (char*)d_ws;
  short* qb16   = (short*)w; w += 2359296;   // [2][4][9216][16] bf16
  short* kb16   = (short*)w; w += 589824;    // [2][4][2304][16] bf16
  short* vb16   = (short*)w; w += 589824;    // [2][64][2304] bf16 (V^T per head)
  short* aob    = (short*)w; w += 2359296;   // [2][4][9216][16] bf16 attention output
  float* mxpart = (float*)w; w += 73728;     // [288][64] per-block x channel sums
  float* papart = (float*)w; w += 49152;     // [96][8][16] per-block attn-out query sums
  float* gfac   = (float*)w; w += 512;
  short* onesb  = (short*)w; w += 2560;      // 1280 bf16 ones

  proj_kernel<<<360, 256, 0, stream>>>(x, Wq, bq, Wk, bk, Wv, bv, qb16, kb16, vb16, onesb, mxpart);
  attn_kernel<<<dim3(96, 4, 2), 256, 0, stream>>>(qb16, kb16, vb16, onesb, aob, papart);
  se_gate_kernel<<<1, 256, 0, stream>>>(mxpart, papart, Wo, bo, W1, b1, W2, b2, Wg, bg, gfac);
  oproj_final_kernel<<<dim3(288, 2), 64, 0, stream>>>(aob, Wo, bo, x, gfac, (float*)d_out);
}